// Round 4
// baseline (304.792 us; speedup 1.0000x reference)
//
#include <hip/hip_runtime.h>

#define NH    16
#define HD    64
#define SQ    2048
#define SKV   2048
#define DM    1024

typedef __attribute__((ext_vector_type(8))) __bf16 bf16x8;
typedef __attribute__((ext_vector_type(4))) __bf16 bf16x4;
typedef __attribute__((ext_vector_type(4))) float  f32x4;

// async global->LDS, 16B per lane; LDS dest = wave-uniform base + lane*16
#define ASYNC16(gp, lp)                                                        \
    __builtin_amdgcn_global_load_lds(                                          \
        (const __attribute__((address_space(1))) void*)(gp),                   \
        (__attribute__((address_space(3))) void*)(lp), 16, 0, 0)

// exp(x/32) = exp2(x * log2(e)/32): single v_mul + v_exp_f32
#if __has_builtin(__builtin_amdgcn_exp2f)
#define EXPS(x) __builtin_amdgcn_exp2f((x) * 0.04508422f)
#else
#define EXPS(x) __expf((x) * 0.03125f)
#endif

// swizzled LDS tile: 64 elems/row, 8 chunks of 8 bf16; chunk' = chunk ^ (row&7)
static __device__ __forceinline__ int swz(int row, int chunk) {
    return (row << 6) + (((chunk) ^ (row & 7)) << 3);
}

static __device__ __forceinline__ bf16x4 cvt4(float4 v) {
    bf16x4 r;
    r[0] = (__bf16)v.x; r[1] = (__bf16)v.y; r[2] = (__bf16)v.z; r[3] = (__bf16)v.w;
    return r;
}

// ---------------------------------------------------------------------------
// kprep_all: one launch for Q-prep, K-prep, W-convert.
// ---------------------------------------------------------------------------
__global__ void kprep_all(const float* __restrict__ q, const float* __restrict__ k,
                          const float* __restrict__ W,
                          __bf16* __restrict__ Qh, __bf16* __restrict__ Kh,
                          __bf16* __restrict__ Wb) {
    int bid = blockIdx.x;
    if (bid < 8192) {
        const float* src = (bid < 4096) ? q : k;
        __bf16* dst = (bid < 4096) ? Qh : Kh;
        size_t g = (size_t)(bid & 4095) * 256 + threadIdx.x;
        size_t o = g * 8;
        int c  = (int)(o & 63);
        int s  = (int)((o >> 6) & 2047);
        int bh = (int)(o >> 17);
        int b = bh >> 4, h = bh & 15;
        const float* p = src + ((size_t)(b * SQ + s)) * DM + h * HD + c;
        float4 v0 = *(const float4*)p;
        float4 v1 = *(const float4*)(p + 4);
        bf16x8 r;
        r[0] = (__bf16)v0.x; r[1] = (__bf16)v0.y; r[2] = (__bf16)v0.z; r[3] = (__bf16)v0.w;
        r[4] = (__bf16)v1.x; r[5] = (__bf16)v1.y; r[6] = (__bf16)v1.z; r[7] = (__bf16)v1.w;
        *(bf16x8*)(dst + o) = r;
    } else {
        int i = (bid - 8192) * 256 + threadIdx.x;
        float4 v = *(const float4*)(W + (size_t)i * 4);
        *(bf16x4*)(Wb + (size_t)i * 4) = cvt4(v);
    }
}

// ---------------------------------------------------------------------------
// kz: Z[k] = sum_q exp(QK^T/32); epilogue writes Vt[bh][d][k] = bf16(V/Z)
// 1024 threads / 16 waves (wave owns 16 k-cols) -> 8 waves/SIMD at 2 blk/CU.
// LDS 49.25 KB. Same schedule as the verified 512-thread version.
// ---------------------------------------------------------------------------
__global__ __launch_bounds__(1024, 8) void kz(const __bf16* __restrict__ Qh,
                                              const __bf16* __restrict__ Kh,
                                              const __bf16* __restrict__ vv,
                                              __bf16* __restrict__ Vt) {
    const float* v = (const float*)vv;   // V input is fp32
    const int bh = blockIdx.x;
    const int kb = blockIdx.y;
    const int b = bh >> 4, h = bh & 15;
    const int t = threadIdx.x;
    const int w = t >> 6, lane = t & 63;
    const int lo16 = lane & 15, quad = lane >> 4;

    __shared__ __bf16 Ks[256 * 64];
    __shared__ __bf16 Qs[2][64 * 64];
    __shared__ float  Zs[256];

    const __bf16* kbase = Kh + ((size_t)bh * SKV + kb * 256) * HD;
    const __bf16* qbase = Qh + (size_t)bh * SQ * HD;

    // stage K 256x64 (2 passes x 1024 lanes x 16B) + Q tile 0 (waves 0-7)
#pragma unroll
    for (int i = 0; i < 2; ++i) {
        int ci = i * 1024 + t;
        int row = ci >> 3;
        int c = (ci & 7) ^ (row & 7);
        ASYNC16(kbase + row * 64 + c * 8, &Ks[i * 8192 + ((t & 960) << 3)]);
    }
    if (w < 8) {
        int ci = t;
        int row = ci >> 3;
        int c = (ci & 7) ^ (row & 7);
        ASYNC16(qbase + row * 64 + c * 8, &Qs[0][(t & 448) << 3]);
    }
    __syncthreads();

    // hoist K fragment (B-operand: n = k-col, kdim = d); wave owns 16 k-cols
    bf16x8 bk[2];
#pragma unroll
    for (int dh = 0; dh < 2; ++dh)
        bk[dh] = *(const bf16x8*)(&Ks[swz(w * 16 + lo16, dh * 4 + quad)]);

    float zacc = 0.f;

    for (int qt = 0; qt < 32; ++qt) {
        const int cur = qt & 1, nxt = cur ^ 1;
        if (qt < 31 && w < 8) {
            int ci = t;
            int row = ci >> 3;
            int c = (ci & 7) ^ (row & 7);
            ASYNC16(qbase + (size_t)(qt + 1) * 64 * HD + row * 64 + c * 8,
                    &Qs[nxt][(t & 448) << 3]);
        }

        __builtin_amdgcn_s_setprio(1);
#pragma unroll
        for (int mt = 0; mt < 4; ++mt) {
            bf16x8 aq0 = *(const bf16x8*)(&Qs[cur][swz(mt * 16 + lo16, quad)]);
            bf16x8 aq1 = *(const bf16x8*)(&Qs[cur][swz(mt * 16 + lo16, 4 + quad)]);
            f32x4 acc = {0.f, 0.f, 0.f, 0.f};
            acc = __builtin_amdgcn_mfma_f32_16x16x32_bf16(aq0, bk[0], acc, 0, 0, 0);
            acc = __builtin_amdgcn_mfma_f32_16x16x32_bf16(aq1, bk[1], acc, 0, 0, 0);
            zacc += EXPS(acc[0]) + EXPS(acc[1]) + EXPS(acc[2]) + EXPS(acc[3]);
        }
        __builtin_amdgcn_s_setprio(0);
        __syncthreads();
    }

    {
        float s = zacc;
        s += __shfl_xor(s, 16, 64);
        s += __shfl_xor(s, 32, 64);
        if (lane < 16) Zs[w * 16 + lane] = s;
    }
    __syncthreads();

    // epilogue: Vt[bh][d][kb*256 + kcol] = bf16(V[k][d] / Z[k])
    // 1024 threads: kcol = t&255, d-quarter = t>>8 (16 d each)
    {
        int kcol = t & 255, dq = t >> 8;
        float rz = 1.0f / Zs[kcol];
        const float* vrow = v + ((size_t)(b * SKV) + kb * 256 + kcol) * DM + h * HD + dq * 16;
        size_t vtb = (size_t)bh * HD * SKV + kb * 256 + kcol;
        float4 a0 = *(const float4*)(vrow + 0);
        float4 a1 = *(const float4*)(vrow + 4);
        float4 a2 = *(const float4*)(vrow + 8);
        float4 a3 = *(const float4*)(vrow + 12);
        float tmp[16] = {a0.x, a0.y, a0.z, a0.w, a1.x, a1.y, a1.z, a1.w,
                         a2.x, a2.y, a2.z, a2.w, a3.x, a3.y, a3.z, a3.w};
#pragma unroll
        for (int j = 0; j < 16; ++j)
            Vt[vtb + (size_t)(dq * 16 + j) * SKV] = (__bf16)(tmp[j] * rz);
    }
}

// ---------------------------------------------------------------------------
// kattn: O[q,:] = sum_k exp(S[q,k]) * Vt[:,k]   (Vt pre-scaled by 1/Z)
// S^T formulation, verified round-1 schedule (one barrier per k-tile).
// 1024 threads / 16 waves (wave owns 16 q-rows) -> 8 waves/SIMD at 2 blk/CU.
// LDS = Ks 16K + Vts 16K + Es 16x2K = 64 KB. Staging: waves 0-7 load Ks,
// waves 8-15 load Vts (one ASYNC16 per thread per tile).
// ---------------------------------------------------------------------------
__global__ __launch_bounds__(1024, 8) void kattn(const __bf16* __restrict__ Qh,
                                                 const __bf16* __restrict__ Kh,
                                                 const __bf16* __restrict__ Vt,
                                                 __bf16* __restrict__ O) {
    const int bh = blockIdx.x;
    const int qb = blockIdx.y;
    const int b = bh >> 4, h = bh & 15;
    const int t = threadIdx.x;
    const int w = t >> 6, lane = t & 63;
    const int lo16 = lane & 15, quad = lane >> 4;

    __shared__ __bf16 Ks[2][64 * 64];
    __shared__ __bf16 Vts[2][64 * 64];
    __shared__ __bf16 Es[16][16 * 64];   // per-wave E strip (2KB each)

    const __bf16* qgb = Qh + ((size_t)bh * SQ + qb * 256 + w * 16) * HD;
    const __bf16* kgbase = Kh + (size_t)bh * SKV * HD;
    const __bf16* vtgbase = Vt + (size_t)bh * HD * SKV;

    // stage K/Vt tile 0: waves 0-7 -> Ks, waves 8-15 -> Vts
    {
        int ci = t & 511;
        int row = ci >> 3;
        int c = (ci & 7) ^ (row & 7);
        if (t < 512)
            ASYNC16(kgbase + row * 64 + c * 8, &Ks[0][(t & 448) << 3]);
        else
            ASYNC16(vtgbase + (size_t)row * SKV + c * 8, &Vts[0][(t & 448) << 3]);
    }

    // Q fragment (B-operand: n = q, kdim = d), direct from global, persists
    bf16x8 qf[2];
#pragma unroll
    for (int dh = 0; dh < 2; ++dh)
        qf[dh] = *(const bf16x8*)(qgb + (size_t)lo16 * HD + (dh * 4 + quad) * 8);

    f32x4 oacc[4];
    f32x4 zero = {0.f, 0.f, 0.f, 0.f};
#pragma unroll
    for (int nt = 0; nt < 4; ++nt)
        oacc[nt] = zero;

    __syncthreads();

    __bf16* Ew = &Es[w][0];

    for (int kt = 0; kt < 32; ++kt) {
        const int cur = kt & 1, nxt = cur ^ 1;
        if (kt < 31) {
            int ci = t & 511;
            int row = ci >> 3;
            int c = (ci & 7) ^ (row & 7);
            if (t < 512)
                ASYNC16(kgbase + (size_t)(kt + 1) * 64 * HD + row * 64 + c * 8,
                        &Ks[nxt][(t & 448) << 3]);
            else
                ASYNC16(vtgbase + (size_t)row * SKV + (kt + 1) * 64 + c * 8,
                        &Vts[nxt][(t & 448) << 3]);
        }

        __builtin_amdgcn_s_setprio(1);
        // S^T = K Q^T / 32; E = exp; packed b64 writes into wave-private strip
#pragma unroll
        for (int ktile = 0; ktile < 4; ++ktile) {
            bf16x8 ak0 = *(const bf16x8*)(&Ks[cur][swz(ktile * 16 + lo16, quad)]);
            bf16x8 ak1 = *(const bf16x8*)(&Ks[cur][swz(ktile * 16 + lo16, 4 + quad)]);
            f32x4 s = zero;
            s = __builtin_amdgcn_mfma_f32_16x16x32_bf16(ak0, qf[0], s, 0, 0, 0);
            s = __builtin_amdgcn_mfma_f32_16x16x32_bf16(ak1, qf[1], s, 0, 0, 0);
            bf16x4 e;
            e[0] = (__bf16)EXPS(s[0]);
            e[1] = (__bf16)EXPS(s[1]);
            e[2] = (__bf16)EXPS(s[2]);
            e[3] = (__bf16)EXPS(s[3]);
            int er = lo16;
            *(bf16x4*)(&Ew[(er << 6) + ((((2 * ktile + (quad >> 1))) ^ (er & 7)) << 3)
                           + (quad & 1) * 4]) = e;
        }

        // O += E @ Vt^T   (intra-wave LDS round trip, no barrier)
#pragma unroll
        for (int kk2 = 0; kk2 < 2; ++kk2) {
            bf16x8 ae = *(const bf16x8*)(&Ew[swz(lo16, kk2 * 4 + quad)]);
#pragma unroll
            for (int nt = 0; nt < 4; ++nt) {
                bf16x8 bv = *(const bf16x8*)(&Vts[cur][swz(nt * 16 + lo16, kk2 * 4 + quad)]);
                oacc[nt] = __builtin_amdgcn_mfma_f32_16x16x32_bf16(ae, bv, oacc[nt], 0, 0, 0);
            }
        }
        __builtin_amdgcn_s_setprio(0);
        __syncthreads();
    }

    size_t obase = ((size_t)(b * SQ) + qb * 256 + w * 16) * DM + h * HD;
#pragma unroll
    for (int nt = 0; nt < 4; ++nt)
#pragma unroll
        for (int r = 0; r < 4; ++r)
            O[obase + (size_t)(quad * 4 + r) * DM + nt * 16 + lo16] =
                (__bf16)oacc[nt][r];
}

// ---------------------------------------------------------------------------
// kproj: out[n, i] = sum_j A[n,j] * W[i,j] + b[i]   (NT GEMM, 128x128 tiles,
// double-buffered). Round-1 verified 256-thread version.
// ---------------------------------------------------------------------------
__global__ __launch_bounds__(256, 2) void kproj(const __bf16* __restrict__ A,
                                                const __bf16* __restrict__ Wb,
                                                const float* __restrict__ bias,
                                                float* __restrict__ out) {
    const int nb = blockIdx.x;
    const int mb = blockIdx.y;
    const int t = threadIdx.x;
    const int w = t >> 6, lane = t & 63;
    const int lo16 = lane & 15, quad = lane >> 4;
    const int wm = w & 1, wn = w >> 1;
    const int wub = (t & 192) << 3;

    __shared__ __bf16 As[2][128 * 64];
    __shared__ __bf16 Bs[2][128 * 64];

    f32x4 acc[4][4];
    f32x4 zero = {0.f, 0.f, 0.f, 0.f};
#pragma unroll
    for (int mt = 0; mt < 4; ++mt)
#pragma unroll
        for (int nt = 0; nt < 4; ++nt)
            acc[mt][nt] = zero;

    const __bf16* abase = A + (size_t)(mb * 128) * DM;
    const __bf16* wbase = Wb + (size_t)(nb * 128) * DM;

#pragma unroll
    for (int i = 0; i < 4; ++i) {
        int ci = i * 256 + t;
        int row = ci >> 3;
        int c = (ci & 7) ^ (row & 7);
        ASYNC16(abase + (size_t)row * DM + c * 8, &As[0][i * 2048 + wub]);
        ASYNC16(wbase + (size_t)row * DM + c * 8, &Bs[0][i * 2048 + wub]);
    }
    __syncthreads();

    for (int kt = 0; kt < 16; ++kt) {
        const int cur = kt & 1, nxt = cur ^ 1;
        if (kt < 15) {
#pragma unroll
            for (int i = 0; i < 4; ++i) {
                int ci = i * 256 + t;
                int row = ci >> 3;
                int c = (ci & 7) ^ (row & 7);
                ASYNC16(abase + (size_t)row * DM + (kt + 1) * 64 + c * 8, &As[nxt][i * 2048 + wub]);
                ASYNC16(wbase + (size_t)row * DM + (kt + 1) * 64 + c * 8, &Bs[nxt][i * 2048 + wub]);
            }
        }

#pragma unroll
        for (int ks = 0; ks < 2; ++ks) {
            bf16x8 av[4], bv[4];
#pragma unroll
            for (int mt = 0; mt < 4; ++mt)
                av[mt] = *(const bf16x8*)(&As[cur][swz(wm * 64 + mt * 16 + lo16, ks * 4 + quad)]);
#pragma unroll
            for (int nt = 0; nt < 4; ++nt)
                bv[nt] = *(const bf16x8*)(&Bs[cur][swz(wn * 64 + nt * 16 + lo16, ks * 4 + quad)]);
#pragma unroll
            for (int mt = 0; mt < 4; ++mt)
#pragma unroll
                for (int nt = 0; nt < 4; ++nt)
                    acc[mt][nt] = __builtin_amdgcn_mfma_f32_16x16x32_bf16(av[mt], bv[nt], acc[mt][nt], 0, 0, 0);
        }
        __syncthreads();
    }

    const int col0 = nb * 128 + wn * 64;
    const int row0 = mb * 128 + wm * 64;
#pragma unroll
    for (int nt = 0; nt < 4; ++nt) {
        float bb = bias[col0 + nt * 16 + lo16];
#pragma unroll
        for (int mt = 0; mt < 4; ++mt)
#pragma unroll
            for (int r = 0; r < 4; ++r)
                out[(size_t)(row0 + mt * 16 + quad * 4 + r) * DM + col0 + nt * 16 + lo16] =
                    acc[mt][nt][r] + bb;
    }
}

// ---------------------------------------------------------------------------
extern "C" void kernel_launch(void* const* d_in, const int* in_sizes, int n_in,
                              void* d_out, int out_size, void* d_ws, size_t ws_size,
                              hipStream_t stream) {
    const float* q    = (const float*)d_in[0];
    const float* k    = (const float*)d_in[1];
    const float* v    = (const float*)d_in[2];
    const float* W    = (const float*)d_in[3];
    const float* bias = (const float*)d_in[4];
    float* out = (float*)d_out;

    char* ws = (char*)d_ws;
    __bf16* Qh = (__bf16*)ws;                          // 16 MB
    __bf16* Kh = (__bf16*)(ws + (16u << 20));          // 16 MB
    __bf16* Vt = (__bf16*)(ws + (32u << 20));          // 16 MB
    __bf16* Wb = (__bf16*)(ws + (48u << 20));          // 2 MB
    __bf16* O  = (__bf16*)(ws + (50u << 20));          // 16 MB

    kprep_all<<<dim3(9216), 256, 0, stream>>>(q, k, W, Qh, Kh, Wb);
    kz       <<<dim3(64, 8), 1024, 0, stream>>>(Qh, Kh, (const __bf16*)v, Vt);
    kattn    <<<dim3(64, 8), 1024, 0, stream>>>(Qh, Kh, Vt, O);
    kproj    <<<dim3(8, 64), 256, 0, stream>>>(O, Wb, bias, out);
}

// Round 5
// 281.809 us; speedup vs baseline: 1.0816x; 1.0816x over previous
//
#include <hip/hip_runtime.h>

#define NH    16
#define HD    64
#define SQ    2048
#define SKV   2048
#define DM    1024

typedef __attribute__((ext_vector_type(8))) __bf16 bf16x8;
typedef __attribute__((ext_vector_type(4))) __bf16 bf16x4;
typedef __attribute__((ext_vector_type(2))) __bf16 bf16x2;
typedef __attribute__((ext_vector_type(4))) float  f32x4;

// async global->LDS, 16B per lane; LDS dest = wave-uniform base + lane*16
#define ASYNC16(gp, lp)                                                        \
    __builtin_amdgcn_global_load_lds(                                          \
        (const __attribute__((address_space(1))) void*)(gp),                   \
        (__attribute__((address_space(3))) void*)(lp), 16, 0, 0)

// exp(x/32) = exp2(x * log2(e)/32): single v_mul + v_exp_f32
#if __has_builtin(__builtin_amdgcn_exp2f)
#define EXPS(x) __builtin_amdgcn_exp2f((x) * 0.04508422f)
#else
#define EXPS(x) __expf((x) * 0.03125f)
#endif

// swizzled LDS tile: 64 elems/row, 8 chunks of 8 bf16; chunk' = chunk ^ (row&7)
static __device__ __forceinline__ int swz(int row, int chunk) {
    return (row << 6) + (((chunk) ^ (row & 7)) << 3);
}

static __device__ __forceinline__ bf16x4 cvt4(float4 v) {
    bf16x4 r;
    r[0] = (__bf16)v.x; r[1] = (__bf16)v.y; r[2] = (__bf16)v.z; r[3] = (__bf16)v.w;
    return r;
}

// RTNE f32 pair -> packed 2xbf16 dword via C-level casts (language-guaranteed
// rounding; round-1 passed with these casts, asm cvt_pk truncated -> 8.8e-3).
static __device__ __forceinline__ unsigned pkbf16(float a, float b) {
    bf16x2 t;
    t[0] = (__bf16)a;
    t[1] = (__bf16)b;
    return __builtin_bit_cast(unsigned, t);
}

// ---------------------------------------------------------------------------
// kprep_all: one launch for Q-prep, K-prep, W-convert.
// ---------------------------------------------------------------------------
__global__ void kprep_all(const float* __restrict__ q, const float* __restrict__ k,
                          const float* __restrict__ W,
                          __bf16* __restrict__ Qh, __bf16* __restrict__ Kh,
                          __bf16* __restrict__ Wb) {
    int bid = blockIdx.x;
    if (bid < 8192) {
        const float* src = (bid < 4096) ? q : k;
        __bf16* dst = (bid < 4096) ? Qh : Kh;
        size_t g = (size_t)(bid & 4095) * 256 + threadIdx.x;
        size_t o = g * 8;
        int c  = (int)(o & 63);
        int s  = (int)((o >> 6) & 2047);
        int bh = (int)(o >> 17);
        int b = bh >> 4, h = bh & 15;
        const float* p = src + ((size_t)(b * SQ + s)) * DM + h * HD + c;
        float4 v0 = *(const float4*)p;
        float4 v1 = *(const float4*)(p + 4);
        bf16x8 r;
        r[0] = (__bf16)v0.x; r[1] = (__bf16)v0.y; r[2] = (__bf16)v0.z; r[3] = (__bf16)v0.w;
        r[4] = (__bf16)v1.x; r[5] = (__bf16)v1.y; r[6] = (__bf16)v1.z; r[7] = (__bf16)v1.w;
        *(bf16x8*)(dst + o) = r;
    } else {
        int i = (bid - 8192) * 256 + threadIdx.x;
        float4 v = *(const float4*)(W + (size_t)i * 4);
        *(bf16x4*)(Wb + (size_t)i * 4) = cvt4(v);
    }
}

// ---------------------------------------------------------------------------
// kz: Z[k] = sum_q exp(QK^T/32); epilogue writes Vt[bh][d][k] = bf16(V/Z)
// 512 threads / 8 waves (round-1 verified best config).
// ---------------------------------------------------------------------------
__global__ __launch_bounds__(512, 4) void kz(const __bf16* __restrict__ Qh,
                                             const __bf16* __restrict__ Kh,
                                             const __bf16* __restrict__ vv,
                                             __bf16* __restrict__ Vt) {
    const float* v = (const float*)vv;   // V input is fp32
    const int bh = blockIdx.x;
    const int kb = blockIdx.y;
    const int b = bh >> 4, h = bh & 15;
    const int t = threadIdx.x;
    const int w = t >> 6, lane = t & 63;
    const int lo16 = lane & 15, quad = lane >> 4;
    const int wub = (t & 448) << 3;          // wave-uniform chunk base (elems)

    __shared__ __bf16 Ks[256 * 64];
    __shared__ __bf16 Qs[2][64 * 64];
    __shared__ float  Zs[256];

    const __bf16* kbase = Kh + ((size_t)bh * SKV + kb * 256) * HD;
    const __bf16* qbase = Qh + (size_t)bh * SQ * HD;

#pragma unroll
    for (int i = 0; i < 4; ++i) {
        int ci = i * 512 + t;
        int row = ci >> 3;
        int c = (ci & 7) ^ (row & 7);
        ASYNC16(kbase + row * 64 + c * 8, &Ks[i * 4096 + wub]);
    }
    {
        int ci = t;
        int row = ci >> 3;
        int c = (ci & 7) ^ (row & 7);
        ASYNC16(qbase + row * 64 + c * 8, &Qs[0][wub]);
    }
    __syncthreads();

    // hoist K fragments (B-operand: n = k-col, kdim = d); wave owns 32 k-cols
    bf16x8 bk[2][2];
#pragma unroll
    for (int nt = 0; nt < 2; ++nt)
#pragma unroll
        for (int dh = 0; dh < 2; ++dh)
            bk[nt][dh] = *(const bf16x8*)(&Ks[swz(w * 32 + nt * 16 + lo16, dh * 4 + quad)]);

    float zacc[2] = {0.f, 0.f};

    for (int qt = 0; qt < 32; ++qt) {
        const int cur = qt & 1, nxt = cur ^ 1;
        if (qt < 31) {
            int ci = t;
            int row = ci >> 3;
            int c = (ci & 7) ^ (row & 7);
            ASYNC16(qbase + (size_t)(qt + 1) * 64 * HD + row * 64 + c * 8,
                    &Qs[nxt][wub]);
        }

        __builtin_amdgcn_s_setprio(1);
#pragma unroll
        for (int mt = 0; mt < 4; ++mt) {
            bf16x8 aq0 = *(const bf16x8*)(&Qs[cur][swz(mt * 16 + lo16, quad)]);
            bf16x8 aq1 = *(const bf16x8*)(&Qs[cur][swz(mt * 16 + lo16, 4 + quad)]);
#pragma unroll
            for (int nt = 0; nt < 2; ++nt) {
                f32x4 acc = {0.f, 0.f, 0.f, 0.f};
                acc = __builtin_amdgcn_mfma_f32_16x16x32_bf16(aq0, bk[nt][0], acc, 0, 0, 0);
                acc = __builtin_amdgcn_mfma_f32_16x16x32_bf16(aq1, bk[nt][1], acc, 0, 0, 0);
                zacc[nt] += EXPS(acc[0]) + EXPS(acc[1]) + EXPS(acc[2]) + EXPS(acc[3]);
            }
        }
        __builtin_amdgcn_s_setprio(0);
        __syncthreads();
    }

#pragma unroll
    for (int nt = 0; nt < 2; ++nt) {
        float s = zacc[nt];
        s += __shfl_xor(s, 16, 64);
        s += __shfl_xor(s, 32, 64);
        if (lane < 16) Zs[w * 32 + nt * 16 + lane] = s;
    }
    __syncthreads();

    // epilogue: Vt[bh][d][kb*256 + kcol] = bf16(V[k][d] / Z[k])
    {
        int kcol = t & 255, dh2 = t >> 8;
        float rz = 1.0f / Zs[kcol];
        const float* vrow = v + ((size_t)(b * SKV) + kb * 256 + kcol) * DM + h * HD + dh2 * 32;
        size_t vtb = (size_t)bh * HD * SKV + kb * 256 + kcol;
#pragma unroll
        for (int dc = 0; dc < 2; ++dc) {
            float4 a0 = *(const float4*)(vrow + dc * 16 + 0);
            float4 a1 = *(const float4*)(vrow + dc * 16 + 4);
            float4 a2 = *(const float4*)(vrow + dc * 16 + 8);
            float4 a3 = *(const float4*)(vrow + dc * 16 + 12);
            float tmp[16] = {a0.x, a0.y, a0.z, a0.w, a1.x, a1.y, a1.z, a1.w,
                             a2.x, a2.y, a2.z, a2.w, a3.x, a3.y, a3.z, a3.w};
#pragma unroll
            for (int j = 0; j < 16; ++j)
                Vt[vtb + (size_t)(dh2 * 32 + dc * 16 + j) * SKV] = (__bf16)(tmp[j] * rz);
        }
    }
}

// ---------------------------------------------------------------------------
// kattn: O[q,:] = sum_k exp(S[q,k]) * Vt[:,k]   (Vt pre-scaled by 1/Z)
// S^T formulation, round-1 schedule (one barrier per k-tile), but E never
// touches LDS: after the swapped QK^T, lane (s,lo16) holds E[k=16T+4s+r][q].
// pkbf16 packs r-pairs with RTNE C-casts; then per (T=0,T=1) register pair,
// permlane32_swap (rows23(a)<->rows01(b)) followed by permlane16_swap
// (odd16(a)<->even16(b)) yields exactly the PV A-fragment dwords:
//   dw0={a0,a2,b0,b2}, dw2={a1,a3,b1,b3} (verified by index algebra twice).
// LDS = Ks 16K + Vts 16K = 32.25 KB; grid-capped at 2 blocks/CU.
// ---------------------------------------------------------------------------
__global__ __launch_bounds__(512, 4) void kattn(const __bf16* __restrict__ Qh,
                                                const __bf16* __restrict__ Kh,
                                                const __bf16* __restrict__ Vt,
                                                __bf16* __restrict__ O) {
    const int bh = blockIdx.x;
    const int qb = blockIdx.y;
    const int b = bh >> 4, h = bh & 15;
    const int t = threadIdx.x;
    const int w = t >> 6, lane = t & 63;
    const int lo16 = lane & 15, quad = lane >> 4;
    const int wub = (t & 448) << 3;

    __shared__ __bf16 Ks[2][64 * 64];
    __shared__ __bf16 Vts[2][64 * 64];

    const __bf16* qgb = Qh + ((size_t)bh * SQ + qb * 256 + w * 32) * HD;
    const __bf16* kgbase = Kh + (size_t)bh * SKV * HD;
    const __bf16* vtgbase = Vt + (size_t)bh * HD * SKV;

    // stage K/Vt tile 0 (one ASYNC16 per thread per buffer)
    {
        int ci = t;
        int row = ci >> 3;
        int c = (ci & 7) ^ (row & 7);
        ASYNC16(kgbase + row * 64 + c * 8, &Ks[0][wub]);
        ASYNC16(vtgbase + (size_t)row * SKV + c * 8, &Vts[0][wub]);
    }

    // Q fragments (B-operand: n = q, kdim = d), direct from global, persist
    bf16x8 qf[2][2];
#pragma unroll
    for (int qt = 0; qt < 2; ++qt)
#pragma unroll
        for (int dh = 0; dh < 2; ++dh)
            qf[qt][dh] = *(const bf16x8*)(qgb + (size_t)(qt * 16 + lo16) * HD
                                          + (dh * 4 + quad) * 8);

    f32x4 oacc[2][4];
    f32x4 zero = {0.f, 0.f, 0.f, 0.f};
#pragma unroll
    for (int qt = 0; qt < 2; ++qt)
#pragma unroll
        for (int nt = 0; nt < 4; ++nt)
            oacc[qt][nt] = zero;

    __syncthreads();

    for (int kt = 0; kt < 32; ++kt) {
        const int cur = kt & 1, nxt = cur ^ 1;
        if (kt < 31) {
            int ci = t;
            int row = ci >> 3;
            int c = (ci & 7) ^ (row & 7);
            ASYNC16(kgbase + (size_t)(kt + 1) * 64 * HD + row * 64 + c * 8,
                    &Ks[nxt][wub]);
            ASYNC16(vtgbase + (size_t)row * SKV + (kt + 1) * 64 + c * 8,
                    &Vts[nxt][wub]);
        }

        __builtin_amdgcn_s_setprio(1);
        // two 32-k groups per 64-k tile; PV consumes each group from registers
#pragma unroll
        for (int g = 0; g < 2; ++g) {
            unsigned pk[2][2][2];   // [T = tile-in-group][qt][pair p]
#pragma unroll
            for (int tt = 0; tt < 2; ++tt) {
                int krow = (g * 2 + tt) * 16 + lo16;
                bf16x8 ak0 = *(const bf16x8*)(&Ks[cur][swz(krow, quad)]);
                bf16x8 ak1 = *(const bf16x8*)(&Ks[cur][swz(krow, 4 + quad)]);
#pragma unroll
                for (int qt = 0; qt < 2; ++qt) {
                    f32x4 s = zero;
                    s = __builtin_amdgcn_mfma_f32_16x16x32_bf16(ak0, qf[qt][0], s, 0, 0, 0);
                    s = __builtin_amdgcn_mfma_f32_16x16x32_bf16(ak1, qf[qt][1], s, 0, 0, 0);
                    pk[tt][qt][0] = pkbf16(EXPS(s[0]), EXPS(s[1]));
                    pk[tt][qt][1] = pkbf16(EXPS(s[2]), EXPS(s[3]));
                }
            }

            // redistribute E to PV A-fragment layout, then PV MFMAs
            bf16x8 ae[2];
#pragma unroll
            for (int qt = 0; qt < 2; ++qt) {
                unsigned j0 = pk[0][qt][0], j2 = pk[1][qt][0];
                unsigned j1 = pk[0][qt][1], j3 = pk[1][qt][1];
                // rows23(j0) <-> rows01(j2)
                asm("v_permlane32_swap_b32 %0, %1" : "+v"(j0), "+v"(j2));
                // odd16(j0) <-> even16(j2)
                asm("v_permlane16_swap_b32 %0, %1" : "+v"(j0), "+v"(j2));
                asm("v_permlane32_swap_b32 %0, %1" : "+v"(j1), "+v"(j3));
                asm("v_permlane16_swap_b32 %0, %1" : "+v"(j1), "+v"(j3));
                uint4 u;
                u.x = j0; u.y = j1; u.z = j2; u.w = j3;
                ae[qt] = __builtin_bit_cast(bf16x8, u);
            }

#pragma unroll
            for (int nt = 0; nt < 4; ++nt) {
                bf16x8 bv = *(const bf16x8*)(&Vts[cur][swz(nt * 16 + lo16, g * 4 + quad)]);
#pragma unroll
                for (int qt = 0; qt < 2; ++qt)
                    oacc[qt][nt] = __builtin_amdgcn_mfma_f32_16x16x32_bf16(ae[qt], bv, oacc[qt][nt], 0, 0, 0);
            }
        }
        __builtin_amdgcn_s_setprio(0);
        __syncthreads();
    }

    size_t obase = ((size_t)(b * SQ) + qb * 256 + w * 32) * DM + h * HD;
#pragma unroll
    for (int qt = 0; qt < 2; ++qt)
#pragma unroll
        for (int nt = 0; nt < 4; ++nt)
#pragma unroll
            for (int r = 0; r < 4; ++r)
                O[obase + (size_t)(qt * 16 + quad * 4 + r) * DM + nt * 16 + lo16] =
                    (__bf16)oacc[qt][nt][r];
}

// ---------------------------------------------------------------------------
// kproj: out[n, i] = sum_j A[n,j] * W[i,j] + b[i]   (NT GEMM, 128x128 tiles,
// double-buffered). Round-1 verified 256-thread version.
// ---------------------------------------------------------------------------
__global__ __launch_bounds__(256, 2) void kproj(const __bf16* __restrict__ A,
                                                const __bf16* __restrict__ Wb,
                                                const float* __restrict__ bias,
                                                float* __restrict__ out) {
    const int nb = blockIdx.x;
    const int mb = blockIdx.y;
    const int t = threadIdx.x;
    const int w = t >> 6, lane = t & 63;
    const int lo16 = lane & 15, quad = lane >> 4;
    const int wm = w & 1, wn = w >> 1;
    const int wub = (t & 192) << 3;

    __shared__ __bf16 As[2][128 * 64];
    __shared__ __bf16 Bs[2][128 * 64];

    f32x4 acc[4][4];
    f32x4 zero = {0.f, 0.f, 0.f, 0.f};
#pragma unroll
    for (int mt = 0; mt < 4; ++mt)
#pragma unroll
        for (int nt = 0; nt < 4; ++nt)
            acc[mt][nt] = zero;

    const __bf16* abase = A + (size_t)(mb * 128) * DM;
    const __bf16* wbase = Wb + (size_t)(nb * 128) * DM;

#pragma unroll
    for (int i = 0; i < 4; ++i) {
        int ci = i * 256 + t;
        int row = ci >> 3;
        int c = (ci & 7) ^ (row & 7);
        ASYNC16(abase + (size_t)row * DM + c * 8, &As[0][i * 2048 + wub]);
        ASYNC16(wbase + (size_t)row * DM + c * 8, &Bs[0][i * 2048 + wub]);
    }
    __syncthreads();

    for (int kt = 0; kt < 16; ++kt) {
        const int cur = kt & 1, nxt = cur ^ 1;
        if (kt < 15) {
#pragma unroll
            for (int i = 0; i < 4; ++i) {
                int ci = i * 256 + t;
                int row = ci >> 3;
                int c = (ci & 7) ^ (row & 7);
                ASYNC16(abase + (size_t)row * DM + (kt + 1) * 64 + c * 8, &As[nxt][i * 2048 + wub]);
                ASYNC16(wbase + (size_t)row * DM + (kt + 1) * 64 + c * 8, &Bs[nxt][i * 2048 + wub]);
            }
        }

#pragma unroll
        for (int ks = 0; ks < 2; ++ks) {
            bf16x8 av[4], bv[4];
#pragma unroll
            for (int mt = 0; mt < 4; ++mt)
                av[mt] = *(const bf16x8*)(&As[cur][swz(wm * 64 + mt * 16 + lo16, ks * 4 + quad)]);
#pragma unroll
            for (int nt = 0; nt < 4; ++nt)
                bv[nt] = *(const bf16x8*)(&Bs[cur][swz(wn * 64 + nt * 16 + lo16, ks * 4 + quad)]);
#pragma unroll
            for (int mt = 0; mt < 4; ++mt)
#pragma unroll
                for (int nt = 0; nt < 4; ++nt)
                    acc[mt][nt] = __builtin_amdgcn_mfma_f32_16x16x32_bf16(av[mt], bv[nt], acc[mt][nt], 0, 0, 0);
        }
        __syncthreads();
    }

    const int col0 = nb * 128 + wn * 64;
    const int row0 = mb * 128 + wm * 64;
#pragma unroll
    for (int nt = 0; nt < 4; ++nt) {
        float bb = bias[col0 + nt * 16 + lo16];
#pragma unroll
        for (int mt = 0; mt < 4; ++mt)
#pragma unroll
            for (int r = 0; r < 4; ++r)
                out[(size_t)(row0 + mt * 16 + quad * 4 + r) * DM + col0 + nt * 16 + lo16] =
                    acc[mt][nt][r] + bb;
    }
}

// ---------------------------------------------------------------------------
extern "C" void kernel_launch(void* const* d_in, const int* in_sizes, int n_in,
                              void* d_out, int out_size, void* d_ws, size_t ws_size,
                              hipStream_t stream) {
    const float* q    = (const float*)d_in[0];
    const float* k    = (const float*)d_in[1];
    const float* v    = (const float*)d_in[2];
    const float* W    = (const float*)d_in[3];
    const float* bias = (const float*)d_in[4];
    float* out = (float*)d_out;

    char* ws = (char*)d_ws;
    __bf16* Qh = (__bf16*)ws;                          // 16 MB
    __bf16* Kh = (__bf16*)(ws + (16u << 20));          // 16 MB
    __bf16* Vt = (__bf16*)(ws + (32u << 20));          // 16 MB
    __bf16* Wb = (__bf16*)(ws + (48u << 20));          // 2 MB
    __bf16* O  = (__bf16*)(ws + (50u << 20));          // 16 MB

    kprep_all<<<dim3(9216), 256, 0, stream>>>(q, k, W, Qh, Kh, Wb);
    kz       <<<dim3(64, 8), 512, 0, stream>>>(Qh, Kh, (const __bf16*)v, Vt);
    kattn    <<<dim3(64, 8), 512, 0, stream>>>(Qh, Kh, Vt, O);
    kproj    <<<dim3(8, 64), 256, 0, stream>>>(O, Wb, bias, out);
}